// Round 14
// baseline (8058.858 us; speedup 1.0000x reference)
//
#include <hip/hip_runtime.h>
#include <math.h>

#define BB 128
#define TT 256
#define TMEL 800
#define EE 512
#define HH 1024
#define MELD 128
#define VV 256

// ws offsets (float units)
#define OFF_PROJ  0u
#define OFF_T1    131072u
#define OFF_WR2   524288u
#define OFF_BB1   1310720u
#define OFF_BB2   1311232u
#define OFF_B2    1311744u
#define OFF_W2C   1315840u
#define OFF_BAR   5510144u
#define OFF_WENCR 5522688u
#define OFF_WIHS  7619840u
#define OFF_W2CR  8668416u
#define OFF_WHHDS 10765568u
#define OFF_WPGS  12862720u
#define OFF_H2B   12936448u
#define OFF_RING  21325056u   /* aliases h1pb (dead after conv2) */

typedef __bf16 bfv8 __attribute__((ext_vector_type(8)));
typedef float f32x4 __attribute__((ext_vector_type(4)));
typedef unsigned u32x4 __attribute__((ext_vector_type(4)));

__device__ __forceinline__ unsigned short f2b(float f){
  union { float f; unsigned u; } v; v.f = f;
  unsigned u = v.u;
  return (unsigned short)((u + 0x7fffu + ((u>>16)&1u)) >> 16);
}
__device__ __forceinline__ float sigm(float x){ return 1.0f/(1.0f+expf(-x)); }

__device__ __forceinline__ f32x4 mfma16(bfv8 a, bfv8 b, f32x4 c){
  return __builtin_amdgcn_mfma_f32_16x16x32_bf16(a, b, c, 0, 0, 0);
}

// ---- fp32 precompute kernels ----

__global__ void k_proj(const float* __restrict__ emb, const float* __restrict__ W,
                       const float* __restrict__ bias, float* __restrict__ proj){
  __shared__ float er[EE];
  int v = blockIdx.x;
  for(int i=threadIdx.x;i<EE;i+=256) er[i]=emb[v*EE+i];
  __syncthreads();
  for(int e=threadIdx.x;e<EE;e+=256){
    const float* wr = W + e*EE;
    float acc=0.f;
    for(int k=0;k<EE;k+=4){
      float4 w4 = *(const float4*)(wr+k);
      acc += er[k]*w4.x + er[k+1]*w4.y + er[k+2]*w4.z + er[k+3]*w4.w;
    }
    proj[v*EE+e] = acc + bias[e];
  }
}

__global__ void k_t1(const float* __restrict__ proj, const float* __restrict__ W1,
                     const float* __restrict__ g1, float* __restrict__ T1){
  __shared__ float pr[EE];
  int v = blockIdx.x; int k3 = blockIdx.y;
  for(int i=threadIdx.x;i<EE;i+=256) pr[i]=proj[v*EE+i];
  __syncthreads();
  const float s = rsqrtf(1.f+1e-5f);
  for(int c=threadIdx.x;c<EE;c+=256){
    float acc=0.f;
    const float* w = W1 + c*EE*3 + k3;
    for(int ci=0;ci<EE;ci++) acc += pr[ci]*w[ci*3];
    T1[(v*3+k3)*EE+c] = g1[c]*s*acc;
  }
}

__global__ void k_wr2(const float* __restrict__ W2, const float* __restrict__ g2,
                      unsigned short* __restrict__ Wr){
  int idx = blockIdx.x*256+threadIdx.x;
  if(idx >= EE*3*EE) return;
  int c = idx/1536; int r = idx%1536; int k3 = r/EE; int ci = r%EE;
  const float s = rsqrtf(1.f+1e-5f);
  Wr[idx] = f2b(g2[c]*s*W2[(c*EE+ci)*3+k3]);
}

__global__ void k_bb(const float* __restrict__ b1,const float* __restrict__ g1,const float* __restrict__ be1,
                     const float* __restrict__ b2,const float* __restrict__ g2,const float* __restrict__ be2,
                     float* __restrict__ bb1, float* __restrict__ bb2){
  int c = threadIdx.x + blockIdx.x*256; if(c>=EE) return;
  const float s = rsqrtf(1.f+1e-5f);
  bb1[c] = g1[c]*s*b1[c] + be1[c];
  bb2[c] = g2[c]*s*b2[c] + be2[c];
}

__global__ void k_b2(const float* __restrict__ bd, const float* __restrict__ Wih,
                     const float* __restrict__ bp, float* __restrict__ b2){
  int j = blockIdx.x*256+threadIdx.x; if(j>=4096) return;
  float acc = bd[j];
  const float* w = Wih + j*MELD;
  for(int m=0;m<MELD;m++) acc += w[m]*bp[m];
  b2[j] = acc;
}

__global__ void k_w2c(const float* __restrict__ Whh, const float* __restrict__ Wih,
                      const float* __restrict__ Wp, float* __restrict__ W2c){
  __shared__ float wl[8][MELD];
  int j0 = blockIdx.x*8; int k = blockIdx.y*256 + threadIdx.x;
  for(int i=threadIdx.x;i<8*MELD;i+=256) wl[i/MELD][i%MELD] = Wih[(j0+i/MELD)*MELD + (i%MELD)];
  __syncthreads();
  float acc[8];
  #pragma unroll
  for(int jj=0;jj<8;jj++) acc[jj]=Whh[(j0+jj)*HH+k];
  for(int m=0;m<MELD;m++){
    float wp = Wp[m*HH+k];
    #pragma unroll
    for(int jj=0;jj<8;jj++) acc[jj] += wl[jj][m]*wp;
  }
  #pragma unroll
  for(int jj=0;jj<8;jj++) W2c[(j0+jj)*HH+k] = acc[jj];
}

// ---- fragment packing ----
__global__ void k_pack(const float* __restrict__ src, unsigned short* __restrict__ dst,
                       int NKT, int K){
  int tile = blockIdx.x;
  int cg = tile>>3, wv = tile&7;
  int tot = NKT*64*8;
  for(int i=threadIdx.x; i<tot; i+=256){
    int kt = i>>9; int l = (i>>3)&63; int e = i&7;
    int j = (wv>>1)*1024 + cg*32 + (wv&1)*16 + (l&15);
    int k = ((l>>4)<<3) + kt*32 + e;
    dst[((size_t)(tile*NKT + kt)*64 + l)*8 + e] = f2b(src[(size_t)j*K + k]);
  }
}

__global__ void k_pack_pg(const float* __restrict__ Wp, const float* __restrict__ Wg,
                          unsigned short* __restrict__ dst){
  int nt = blockIdx.x; // 0..8
  for(int i=threadIdx.x; i<32*64*8; i+=256){
    int kt = i>>9; int l = (i>>3)&63; int e = i&7;
    int n = nt*16 + (l&15);
    int k = ((l>>4)<<3) + kt*32 + e;
    float v = (n<MELD)? Wp[(size_t)n*HH+k] : (n==MELD? Wg[k] : 0.f);
    dst[((size_t)(nt*32 + kt)*64 + l)*8 + e] = f2b(v);
  }
}

// ---- conv path ----

__global__ void k_pad(unsigned short* __restrict__ h1pb){
  int idx = blockIdx.x*256+threadIdx.x;
  int c = idx & 511; int b = idx >> 9;
  h1pb[((size_t)b*258)*EE + c] = 0;
  h1pb[((size_t)b*258 + 257)*EE + c] = 0;
}

__global__ void k_conv1(const int* __restrict__ x, const float* __restrict__ T1,
                        const float* __restrict__ bb1, unsigned short* __restrict__ h1pb){
  int idx = blockIdx.x*256+threadIdx.x;
  int c = idx & 511; int bt = idx >> 9; int t = bt & 255; int b = bt >> 8;
  float acc = bb1[c];
  if(t > 0)    acc += T1[(size_t)(x[b*TT+t-1]*3+0)*EE+c];
               acc += T1[(size_t)(x[b*TT+t  ]*3+1)*EE+c];
  if(t < TT-1) acc += T1[(size_t)(x[b*TT+t+1]*3+2)*EE+c];
  h1pb[((size_t)b*258 + t + 1)*EE + c] = f2b(fmaxf(acc, 0.f));
}

template<int NKT>
__device__ __forceinline__ void mm_seg_stream(const unsigned short* A, int lda,
    const unsigned short* Wrow, f32x4& acc0, f32x4& acc1, int l, int wv){
  int r0 = wv*32 + (l&15);
  int k8 = (l>>4)*8;
  const unsigned short* a0 = A + (size_t)r0*lda + k8;
  const unsigned short* a1 = a0 + 16*lda;
  const unsigned short* wp = Wrow + k8;
  #pragma unroll
  for(int kt=0;kt<NKT;kt++){
    bfv8 bv = *(const bfv8*)(const void*)(wp + kt*32);
    acc0 = mfma16(*(const bfv8*)(const void*)(a0 + kt*32), bv, acc0);
    acc1 = mfma16(*(const bfv8*)(const void*)(a1 + kt*32), bv, acc1);
  }
}

__global__ __launch_bounds__(256,2) void k_conv2mm(const unsigned short* __restrict__ h1pb,
    const unsigned short* __restrict__ Wr2b, const float* __restrict__ bb2,
    unsigned short* __restrict__ h2b){
  int b = blockIdx.x;    // 0..127
  int th = blockIdx.y;   // 0..1
  int nt = blockIdx.z;   // 0..31
  int tid=threadIdx.x; int wv=tid>>6, l=tid&63;
  const unsigned short* A = h1pb + ((size_t)b*258 + th*128)*EE;
  const unsigned short* Wrow = Wr2b + (size_t)(nt*16+(l&15))*1536;
  f32x4 acc0={0,0,0,0}, acc1={0,0,0,0};
  mm_seg_stream<48>(A, EE, Wrow, acc0, acc1, l, wv);
  int rr=(l>>4)*4, cc=l&15;
  int n = nt*16+cc;
  float bias = bb2[n];
  #pragma unroll
  for(int mi=0;mi<2;mi++){
    f32x4 acc = mi?acc1:acc0;
    int tb = th*128 + wv*32 + mi*16 + rr;
    #pragma unroll
    for(int q=0;q<4;q++){
      float v = fmaxf(acc[q]+bias, 0.f);
      h2b[((size_t)(tb+q)*BB + b)*EE + n] = f2b(v);
    }
  }
}

// ---- barrier.
// FAST arrive: 2-level TREE of workgroup-scope RMWs (atomics execute at the
// XCD L2 -- same primitive class round 12 proved): 4 sub-counters on distinct
// 128B lines (8 serialized RMWs each, parallel across lines) -> mid counter
// (4 RMWs) -> one agent-scope gen increment. Replaces round 12's 32-deep
// serialized same-line chain. Re-arm is generation-safe: a WG can only
// re-increment a sub-counter after observing gen (agent), which happens after
// the mid/gen propagation completed.
// WAIT: agent-scope poll of gen by thread0 ONLY (L1-bypassing -- rounds 11/13
// proved sc0/workgroup-scope polling can spin forever on a stale L1 line).
// SLOW mode: round-8 agent-scope counting barrier, progress under any
// placement. ----
__device__ __forceinline__ void g_arrive(unsigned int* cnt, unsigned int* tree,
                                         unsigned int* gen, int cg, bool fastp){
  __syncthreads();   // drains vmcnt: h-stores are in L2 (fast) / at CP (slow)
  if(threadIdx.x == 0){
    if(fastp){
      unsigned int* sub = tree + (cg>>3)*32;     // 4 subs, 128B apart
      unsigned int old = __hip_atomic_fetch_add(sub, 1u, __ATOMIC_RELAXED, __HIP_MEMORY_SCOPE_WORKGROUP);
      if(old == 7u){
        __hip_atomic_store(sub, 0u, __ATOMIC_RELAXED, __HIP_MEMORY_SCOPE_WORKGROUP);
        unsigned int mo = __hip_atomic_fetch_add(tree + 128, 1u, __ATOMIC_RELAXED, __HIP_MEMORY_SCOPE_WORKGROUP);
        if(mo == 3u){
          __hip_atomic_store(tree + 128, 0u, __ATOMIC_RELAXED, __HIP_MEMORY_SCOPE_WORKGROUP);
          __hip_atomic_fetch_add(gen, 1u, __ATOMIC_RELAXED, __HIP_MEMORY_SCOPE_AGENT);
        }
      }
    } else {
      unsigned int old = __hip_atomic_fetch_add(cnt, 1u, __ATOMIC_RELAXED, __HIP_MEMORY_SCOPE_AGENT);
      if(old == 31u){
        __hip_atomic_store(cnt, 0u, __ATOMIC_RELAXED, __HIP_MEMORY_SCOPE_AGENT);
        __hip_atomic_fetch_add(gen, 1u, __ATOMIC_RELAXED, __HIP_MEMORY_SCOPE_AGENT);
      }
    }
  }
}
__device__ __forceinline__ void g_wait(unsigned int* gen, unsigned int target){
  if(threadIdx.x == 0){
    while(__hip_atomic_load(gen, __ATOMIC_RELAXED, __HIP_MEMORY_SCOPE_AGENT) < target)
      __builtin_amdgcn_s_sleep(1);
  }
  asm volatile("" ::: "memory");
  __syncthreads();
}

// ---- h transport (round 12, proven): FAST = workgroup-scope store to XCD L2
// + sc0 reads (freshness via slot rotation > L1 capacity); SLOW = agent-scope
// at the coherence point. ----
__device__ __forceinline__ void h_store(unsigned int* ptr, unsigned int val, bool fastp){
  if(fastp) __hip_atomic_store(ptr, val, __ATOMIC_RELAXED, __HIP_MEMORY_SCOPE_WORKGROUP);
  else      __hip_atomic_store(ptr, val, __ATOMIC_RELAXED, __HIP_MEMORY_SCOPE_AGENT);
}
__device__ __forceinline__ void h_store64(unsigned long long* ptr, unsigned long long val, bool fastp){
  if(fastp) __hip_atomic_store(ptr, val, __ATOMIC_RELAXED, __HIP_MEMORY_SCOPE_WORKGROUP);
  else      __hip_atomic_store(ptr, val, __ATOMIC_RELAXED, __HIP_MEMORY_SCOPE_AGENT);
}

__device__ __forceinline__ void stage_h(unsigned short* hs, const unsigned short* slotp,
                                        int bg, int tid, bool fastp){
  if(fastp){
    const char* base = (const char*)(slotp + (size_t)(bg*16)*HH);
    #pragma unroll
    for(int jj=0;jj<2;jj++){
      int i0 = tid + (jj*2+0)*512, i1 = tid + (jj*2+1)*512;
      int r0 = i0>>7, c0 = i0&127, r1 = i1>>7, c1 = i1&127;
      int o0 = r0*2048 + c0*16,     o1 = r1*2048 + c1*16;
      u32x4 v0, v1;
      asm volatile(
        "global_load_dwordx4 %0, %2, off sc0\n\t"
        "global_load_dwordx4 %1, %3, off sc0\n\t"
        "s_waitcnt vmcnt(0)"
        : "=&v"(v0), "=&v"(v1)
        : "v"(base + o0), "v"(base + o1)
        : "memory");
      *(u32x4*)((char*)hs + (o0 ^ ((r0&7)<<4))) = v0;
      *(u32x4*)((char*)hs + (o1 ^ ((r1&7)<<4))) = v1;
    }
  } else {
    for(int i = tid; i < 4096; i += 512){
      int r = i >> 8, c8 = i & 255;
      const unsigned long long* p =
        (const unsigned long long*)(slotp + (size_t)(bg*16+r)*HH + c8*4);
      unsigned long long v = __hip_atomic_load(p, __ATOMIC_RELAXED, __HIP_MEMORY_SCOPE_AGENT);
      *(unsigned long long*)((char*)hs + ((r*2048 + c8*8) ^ ((r&7)<<4))) = v;
    }
  }
}

// ---- persistent recurrence: 256 WGs = 8 batch-groups x 32 col-groups.
// bg = bid&7: same-XCD group under round-robin dispatch (detected, not
// assumed; non-uniform groups fall back to the round-8 path). ----
__global__ __launch_bounds__(512,1) void k_recur(
  const unsigned short* __restrict__ h2b, unsigned short* __restrict__ ring,
  const unsigned short* __restrict__ WencR, const unsigned short* __restrict__ WihS,
  const unsigned short* __restrict__ W2cR, const unsigned short* __restrict__ WhhdS,
  const unsigned short* __restrict__ WpgS,
  const float* __restrict__ bhe, const float* __restrict__ bd, const float* __restrict__ b2,
  const float* __restrict__ bp, const float* __restrict__ bgp,
  unsigned int* __restrict__ bar,
  const int* __restrict__ tlen, const int* __restrict__ mlen,
  float* __restrict__ outmel, float* __restrict__ outgate)
{
  __shared__ __align__(16) unsigned short hs[16*1024];  // 32KB
  __shared__ __align__(16) unsigned short Xs[16*512];   // 16KB
  __shared__ float Gs[16][132];
  __shared__ unsigned s_ids[32];
  __shared__ int s_fast;

  const int bid = blockIdx.x;
  const int bg = bid & 7, cg = bid >> 3;
  const int tid = threadIdx.x;
  const int wvi = tid >> 6, l = tid & 63;
  const int tile = cg*8 + wvi;
  unsigned int* cnt  = bar + bg*32;
  unsigned int* gen  = bar + 256 + bg*32;
  unsigned int* xtab = bar + 512;
  unsigned int* tree = bar + 1024 + bg*192;   // 4 subs (128B apart) + mid line
  unsigned int ge = 1;

  // ---- placement detection (cannot hang: all 256 co-resident WGs store
  // their id before any barrier) ----
  if(tid == 0){
    unsigned id;
    asm volatile("s_getreg_b32 %0, hwreg(HW_REG_XCC_ID)" : "=s"(id));
    __hip_atomic_store(xtab + bid, id + 1u, __ATOMIC_RELAXED, __HIP_MEMORY_SCOPE_AGENT);
  }
  if(tid < 32){
    unsigned v;
    do {
      v = __hip_atomic_load(xtab + (tid*8 + bg), __ATOMIC_RELAXED, __HIP_MEMORY_SCOPE_AGENT);
    } while(v == 0u);
    s_ids[tid] = v;
  }
  __syncthreads();
  if(tid == 0){
    int f = 1;
    for(int i=1;i<32;i++) if(s_ids[i] != s_ids[0]) f = 0;
    s_fast = f;
  }
  __syncthreads();
  const bool fastp = (s_fast != 0);

  const int fr = l & 15;
  const int hswz = (fr & 7) << 4;
  const int hbase = fr*2048 + ((l>>4)<<4);
  const int xbase = fr*1024 + ((l>>4)<<4);

  const int lr = tid >> 4;
  const int lc = (tid & 15) * 2;
  const int hcol = cg*32 + lc;
  float cs0 = 0.f, cs1 = 0.f;
  unsigned int hp = 0u;
  int mylen = 0;
  if(tid < 256) mylen = tlen[bg*16 + lr];

  // zero enc h_0 (slot 100)
  if(tid < 128){
    int r = tid >> 3, c4 = (tid & 7) * 4;
    unsigned long long* p = (unsigned long long*)
      (ring + (size_t)100*BB*HH + (size_t)(bg*16+r)*HH + cg*32 + c4);
    h_store64(p, 0ull, fastp);
  }
  g_arrive(cnt, tree, gen, cg, fastp);

  f32x4 bw[32];

  // ================= encoder: 256 steps =================
  {
    const f32x4* wsrc = (const f32x4*)(const void*)(WencR + ((size_t)(tile*32)*64 + l)*8);
    #pragma unroll
    for(int kt=0;kt<32;kt++) bw[kt] = wsrc[kt*64];
    #pragma unroll
    for(int kt=0;kt<32;kt++) asm volatile("" : "+v"(bw[kt]));
  }

  float ei0=0,ei1=0,ef0=0,ef1=0,eg0=0,eg1=0,eo0=0,eo1=0;
  if(tid < 256){
    ei0=bhe[hcol];      ei1=bhe[hcol+1];
    ef0=bhe[HH+hcol];   ef1=bhe[HH+hcol+1];
    eg0=bhe[2*HH+hcol]; eg1=bhe[2*HH+hcol+1];
    eo0=bhe[3*HH+hcol]; eo1=bhe[3*HH+hcol+1];
  }

  #pragma unroll 1
  for(int t=0;t<TT;t++){
    {
      const uint4* src = (const uint4*)(h2b + (size_t)(t*BB + bg*16)*EE);
      for(int i = tid; i < 1024; i += 512){
        int r = i >> 6, c16 = i & 63;
        uint4 v = src[r*64 + c16];
        *(uint4*)((char*)Xs + ((r*1024 + c16*16) ^ ((r&7)<<4))) = v;
      }
    }
    __syncthreads();
    f32x4 a0 = {0.f,0.f,0.f,0.f}, a1 = {0.f,0.f,0.f,0.f};
    {
      const unsigned short* wsrc = WihS + (size_t)tile*16*64*8;
      #pragma unroll
      for(int kt=0;kt<16;kt+=2){
        bfv8 wf0 = *(const bfv8*)(const void*)(wsrc + ((size_t)kt*64 + l)*8);
        bfv8 wf1 = *(const bfv8*)(const void*)(wsrc + ((size_t)(kt+1)*64 + l)*8);
        bfv8 xv0 = *(const bfv8*)(const void*)((const char*)Xs + ((xbase + kt*64) ^ hswz));
        bfv8 xv1 = *(const bfv8*)(const void*)((const char*)Xs + ((xbase + (kt+1)*64) ^ hswz));
        a0 = mfma16(xv0, wf0, a0);
        a1 = mfma16(xv1, wf1, a1);
      }
    }
    g_wait(gen, ge);   // h_t ready
    stage_h(hs, ring + (size_t)(100 + (t&1))*BB*HH, bg, tid, fastp);
    __syncthreads();
    #pragma unroll
    for(int kt=0;kt<32;kt+=2){
      bfv8 hv0 = *(const bfv8*)(const void*)((const char*)hs + ((hbase + kt*64) ^ hswz));
      bfv8 hv1 = *(const bfv8*)(const void*)((const char*)hs + ((hbase + (kt+1)*64) ^ hswz));
      a0 = mfma16(hv0, __builtin_bit_cast(bfv8, bw[kt]), a0);
      a1 = mfma16(hv1, __builtin_bit_cast(bfv8, bw[kt+1]), a1);
    }
    {
      f32x4 acc = a0 + a1;
      int rr = (l>>4)*4;
      #pragma unroll
      for(int q=0;q<4;q++) Gs[rr+q][wvi*16 + fr] = acc[q];
    }
    __syncthreads();
    if(tid < 256){
      float gi0 = Gs[lr][lc]    + ei0, gi1 = Gs[lr][lc+1] + ei1;
      float gf0 = Gs[lr][32+lc] + ef0, gf1 = Gs[lr][33+lc] + ef1;
      float gg0 = Gs[lr][64+lc] + eg0, gg1 = Gs[lr][65+lc] + eg1;
      float go0 = Gs[lr][96+lc] + eo0, go1 = Gs[lr][97+lc] + eo1;
      float c20 = sigm(gf0)*cs0 + sigm(gi0)*tanhf(gg0);
      float c21 = sigm(gf1)*cs1 + sigm(gi1)*tanhf(gg1);
      float h20 = sigm(go0)*tanhf(c20);
      float h21 = sigm(go1)*tanhf(c21);
      if(t < mylen){
        cs0 = c20; cs1 = c21;
        hp = (unsigned)f2b(h20) | ((unsigned)f2b(h21)<<16);
      }
      unsigned short* outslot = (t==TT-1) ? (ring + (size_t)99*BB*HH)
                                          : (ring + (size_t)(100 + ((t+1)&1))*BB*HH);
      h_store((unsigned int*)(outslot + (size_t)(bg*16+lr)*HH + hcol), hp, fastp);
    }
    g_arrive(cnt, tree, gen, cg, fastp); ge++;
  }

  // ================= decoder: 800 steps =================
  {
    const f32x4* wsrc = (const f32x4*)(const void*)(W2cR + ((size_t)(tile*32)*64 + l)*8);
    #pragma unroll
    for(int kt=0;kt<32;kt++) bw[kt] = wsrc[kt*64];
    #pragma unroll
    for(int kt=0;kt<32;kt++) asm volatile("" : "+v"(bw[kt]));
  }

  float di0=0,di1=0,df0=0,df1=0,dg0=0,dg1=0,do0=0,do1=0;
  if(tid < 256){
    di0=b2[hcol];      di1=b2[hcol+1];
    df0=b2[HH+hcol];   df1=b2[HH+hcol+1];
    dg0=b2[2*HH+hcol]; dg1=b2[2*HH+hcol+1];
    do0=b2[3*HH+hcol]; do1=b2[3*HH+hcol+1];
  }

  #pragma unroll 1
  for(int t=0;t<TMEL;t++){
    g_wait(gen, ge);   // s_t ready
    const unsigned short* slotin = (t==0) ? ring + (size_t)99*BB*HH
                                          : ring + (size_t)((t-1)%100)*BB*HH;
    stage_h(hs, slotin, bg, tid, fastp);
    __syncthreads();
    f32x4 a0 = {0.f,0.f,0.f,0.f}, a1 = {0.f,0.f,0.f,0.f};
    if(t == 0){
      const unsigned short* wsrc = WhhdS + (size_t)tile*32*64*8;
      #pragma unroll
      for(int kt=0;kt<32;kt+=2){
        bfv8 wf0 = *(const bfv8*)(const void*)(wsrc + ((size_t)kt*64 + l)*8);
        bfv8 wf1 = *(const bfv8*)(const void*)(wsrc + ((size_t)(kt+1)*64 + l)*8);
        bfv8 hv0 = *(const bfv8*)(const void*)((const char*)hs + ((hbase + kt*64) ^ hswz));
        bfv8 hv1 = *(const bfv8*)(const void*)((const char*)hs + ((hbase + (kt+1)*64) ^ hswz));
        a0 = mfma16(hv0, wf0, a0);
        a1 = mfma16(hv1, wf1, a1);
      }
    } else {
      #pragma unroll
      for(int kt=0;kt<32;kt+=2){
        bfv8 hv0 = *(const bfv8*)(const void*)((const char*)hs + ((hbase + kt*64) ^ hswz));
        bfv8 hv1 = *(const bfv8*)(const void*)((const char*)hs + ((hbase + (kt+1)*64) ^ hswz));
        a0 = mfma16(hv0, __builtin_bit_cast(bfv8, bw[kt]), a0);
        a1 = mfma16(hv1, __builtin_bit_cast(bfv8, bw[kt+1]), a1);
      }
    }
    {
      f32x4 acc = a0 + a1;
      int rr = (l>>4)*4;
      #pragma unroll
      for(int q=0;q<4;q++) Gs[rr+q][wvi*16 + fr] = acc[q];
    }
    __syncthreads();
    if(tid < 256){
      float bi0=di0,bi1=di1,bf0=df0,bf1=df1,bg0=dg0,bg1=dg1,bo0=do0,bo1=do1;
      if(t==0){
        bi0=bd[hcol];      bi1=bd[hcol+1];
        bf0=bd[HH+hcol];   bf1=bd[HH+hcol+1];
        bg0=bd[2*HH+hcol]; bg1=bd[2*HH+hcol+1];
        bo0=bd[3*HH+hcol]; bo1=bd[3*HH+hcol+1];
      }
      float gi0 = Gs[lr][lc]    + bi0, gi1 = Gs[lr][lc+1] + bi1;
      float gf0 = Gs[lr][32+lc] + bf0, gf1 = Gs[lr][33+lc] + bf1;
      float gg0 = Gs[lr][64+lc] + bg0, gg1 = Gs[lr][65+lc] + bg1;
      float go0 = Gs[lr][96+lc] + bo0, go1 = Gs[lr][97+lc] + bo1;
      float c20 = sigm(gf0)*cs0 + sigm(gi0)*tanhf(gg0);
      float c21 = sigm(gf1)*cs1 + sigm(gi1)*tanhf(gg1);
      cs0 = c20; cs1 = c21;
      float h20 = sigm(go0)*tanhf(c20);
      float h21 = sigm(go1)*tanhf(c21);
      unsigned int hn = (unsigned)f2b(h20) | ((unsigned)f2b(h21)<<16);
      unsigned short* outslot = ring + (size_t)(t%100)*BB*HH;
      h_store((unsigned int*)(outslot + (size_t)(bg*16+lr)*HH + hcol), hn, fastp);
    }
    g_arrive(cnt, tree, gen, cg, fastp); ge++;

    if((t%100)==99){
      g_wait(gen, ge);   // all 100 slots final
      int tbase = t - 99;
      #pragma unroll 1
      for(int s = cg; s < 100; s += 32){
        stage_h(hs, ring + (size_t)s*BB*HH, bg, tid, fastp);
        __syncthreads();
        int tout = tbase + s;
        #pragma unroll 1
        for(int pass=0; pass<2; pass++){
          int nt = (pass==0) ? wvi : 8;
          if(pass==1 && wvi!=0) break;
          const unsigned short* wsrc = WpgS + (size_t)nt*32*64*8;
          f32x4 acc = {0.f,0.f,0.f,0.f};
          #pragma unroll
          for(int kt=0;kt<32;kt++){
            bfv8 wf = *(const bfv8*)(const void*)(wsrc + ((size_t)kt*64 + l)*8);
            bfv8 hv = *(const bfv8*)(const void*)((const char*)hs + ((hbase + kt*64) ^ hswz));
            acc = mfma16(hv, wf, acc);
          }
          int n = nt*16 + fr;
          #pragma unroll
          for(int q=0;q<4;q++){
            int b = bg*16 + (l>>4)*4 + q;
            bool msk = tout > mlen[b];
            if(n < MELD)
              outmel[((size_t)b*TMEL + tout)*MELD + n] = msk ? 0.f : acc[q]+bp[n];
            else if(n == MELD)
              outgate[(size_t)b*TMEL + tout] = msk ? 1000.f : acc[q]+bgp[0];
          }
        }
        __syncthreads();
      }
      g_arrive(cnt, tree, gen, cg, fastp); ge++;
    }
  }
}

__global__ void k_mask(const int* __restrict__ mlen, float* __restrict__ om){
  int idx=blockIdx.x*256+threadIdx.x; if(idx>=BB*TMEL) return;
  int b=idx/TMEL, t=idx%TMEL;
  om[idx] = (t > mlen[b]) ? 1.f : 0.f;
}

extern "C" void kernel_launch(void* const* d_in, const int* in_sizes, int n_in,
                              void* d_out, int out_size, void* d_ws, size_t ws_size,
                              hipStream_t stream){
  (void)in_sizes; (void)n_in; (void)out_size; (void)ws_size;
  const int*   x    = (const int*)d_in[0];
  const int*   tlen = (const int*)d_in[1];
  const int*   mlen = (const int*)d_in[3];
  const float* emb  = (const float*)d_in[4];
  const float* elW  = (const float*)d_in[5];
  const float* elb  = (const float*)d_in[6];
  const float* c1W  = (const float*)d_in[7];
  const float* c1b  = (const float*)d_in[8];
  const float* g1   = (const float*)d_in[9];
  const float* be1  = (const float*)d_in[10];
  const float* c2W  = (const float*)d_in[11];
  const float* c2b  = (const float*)d_in[12];
  const float* g2   = (const float*)d_in[13];
  const float* be2  = (const float*)d_in[14];
  const float* Wihe = (const float*)d_in[15];
  const float* Whhe = (const float*)d_in[16];
  const float* bhe  = (const float*)d_in[17];
  const float* Wihd = (const float*)d_in[18];
  const float* Whhd = (const float*)d_in[19];
  const float* bhd  = (const float*)d_in[20];
  const float* Wp   = (const float*)d_in[21];
  const float* bp   = (const float*)d_in[22];
  const float* Wg   = (const float*)d_in[23];
  const float* bg   = (const float*)d_in[24];

  float* ws = (float*)d_ws;
  float* proj = ws + OFF_PROJ;
  float* T1   = ws + OFF_T1;
  unsigned short* Wr2b = (unsigned short*)(ws + OFF_WR2);
  float* bb1 = ws + OFF_BB1;
  float* bb2 = ws + OFF_BB2;
  float* b2  = ws + OFF_B2;
  float* W2c = ws + OFF_W2C;
  unsigned int* bar = (unsigned int*)(ws + OFF_BAR);
  unsigned short* WencR = (unsigned short*)(ws + OFF_WENCR);
  unsigned short* WihS  = (unsigned short*)(ws + OFF_WIHS);
  unsigned short* W2cR  = (unsigned short*)(ws + OFF_W2CR);
  unsigned short* WhhdS = (unsigned short*)(ws + OFF_WHHDS);
  unsigned short* WpgS  = (unsigned short*)(ws + OFF_WPGS);
  unsigned short* h2b   = (unsigned short*)(ws + OFF_H2B);
  unsigned short* h1pb  = (unsigned short*)(ws + OFF_RING); // conv scratch
  unsigned short* ring  = (unsigned short*)(ws + OFF_RING); // alias after conv2

  float* outmel  = (float*)d_out;
  float* outgate = outmel + (size_t)BB*TMEL*MELD;
  float* outmask = outgate + (size_t)BB*TMEL;

  hipMemsetAsync(bar, 0, 16384, stream);   // cnt/gen + xtab + tree counters

  k_proj<<<VV,256,0,stream>>>(emb, elW, elb, proj);
  k_t1<<<dim3(VV,3),256,0,stream>>>(proj, c1W, g1, T1);
  k_wr2<<<(EE*3*EE+255)/256,256,0,stream>>>(c2W, g2, Wr2b);
  k_bb<<<2,256,0,stream>>>(c1b,g1,be1,c2b,g2,be2,bb1,bb2);
  k_b2<<<16,256,0,stream>>>(bhd, Wihd, bp, b2);
  k_w2c<<<dim3(4096/8,HH/256),256,0,stream>>>(Whhd, Wihd, Wp, W2c);
  k_pack<<<256,256,0,stream>>>(Whhe, WencR, 32, 1024);
  k_pack<<<256,256,0,stream>>>(Wihe, WihS, 16, 512);
  k_pack<<<256,256,0,stream>>>(W2c,  W2cR, 32, 1024);
  k_pack<<<256,256,0,stream>>>(Whhd, WhhdS, 32, 1024);
  k_pack_pg<<<9,256,0,stream>>>(Wp, Wg, WpgS);
  k_pad<<<256,256,0,stream>>>(h1pb);
  k_conv1<<<65536,256,0,stream>>>(x, T1, bb1, h1pb);
  k_conv2mm<<<dim3(BB,2,32),256,0,stream>>>(h1pb, Wr2b, bb2, h2b);

  void* kargs[] = {
    (void*)&h2b, (void*)&ring, (void*)&WencR, (void*)&WihS, (void*)&W2cR, (void*)&WhhdS,
    (void*)&WpgS, (void*)&bhe, (void*)&bhd, (void*)&b2, (void*)&bp, (void*)&bg,
    (void*)&bar, (void*)&tlen, (void*)&mlen, (void*)&outmel, (void*)&outgate
  };
  hipLaunchCooperativeKernel((void*)k_recur, dim3(256), dim3(512), kargs, 0u, stream);

  k_mask<<<(BB*TMEL+255)/256,256,0,stream>>>(mlen, outmask);
}

// Round 15
// 7794.651 us; speedup vs baseline: 1.0339x; 1.0339x over previous
//
#include <hip/hip_runtime.h>
#include <math.h>

#define BB 128
#define TT 256
#define TMEL 800
#define EE 512
#define HH 1024
#define MELD 128
#define VV 256

// ws offsets (float units)
#define OFF_PROJ  0u
#define OFF_T1    131072u
#define OFF_WR2   524288u
#define OFF_BB1   1310720u
#define OFF_BB2   1311232u
#define OFF_B2    1311744u
#define OFF_W2C   1315840u
#define OFF_BAR   5510144u
#define OFF_WENCR 5522688u
#define OFF_WIHS  7619840u
#define OFF_W2CR  8668416u
#define OFF_WHHDS 10765568u
#define OFF_WPGS  12862720u
#define OFF_H2B   12936448u
#define OFF_RING  21325056u   /* aliases h1pb (dead after conv2) */

typedef __bf16 bfv8 __attribute__((ext_vector_type(8)));
typedef float f32x4 __attribute__((ext_vector_type(4)));
typedef unsigned u32x4 __attribute__((ext_vector_type(4)));

__device__ __forceinline__ unsigned short f2b(float f){
  union { float f; unsigned u; } v; v.f = f;
  unsigned u = v.u;
  return (unsigned short)((u + 0x7fffu + ((u>>16)&1u)) >> 16);
}
__device__ __forceinline__ float sigm(float x){ return 1.0f/(1.0f+expf(-x)); }

__device__ __forceinline__ f32x4 mfma16(bfv8 a, bfv8 b, f32x4 c){
  return __builtin_amdgcn_mfma_f32_16x16x32_bf16(a, b, c, 0, 0, 0);
}

// ---- fp32 precompute kernels ----

__global__ void k_proj(const float* __restrict__ emb, const float* __restrict__ W,
                       const float* __restrict__ bias, float* __restrict__ proj){
  __shared__ float er[EE];
  int v = blockIdx.x;
  for(int i=threadIdx.x;i<EE;i+=256) er[i]=emb[v*EE+i];
  __syncthreads();
  for(int e=threadIdx.x;e<EE;e+=256){
    const float* wr = W + e*EE;
    float acc=0.f;
    for(int k=0;k<EE;k+=4){
      float4 w4 = *(const float4*)(wr+k);
      acc += er[k]*w4.x + er[k+1]*w4.y + er[k+2]*w4.z + er[k+3]*w4.w;
    }
    proj[v*EE+e] = acc + bias[e];
  }
}

__global__ void k_t1(const float* __restrict__ proj, const float* __restrict__ W1,
                     const float* __restrict__ g1, float* __restrict__ T1){
  __shared__ float pr[EE];
  int v = blockIdx.x; int k3 = blockIdx.y;
  for(int i=threadIdx.x;i<EE;i+=256) pr[i]=proj[v*EE+i];
  __syncthreads();
  const float s = rsqrtf(1.f+1e-5f);
  for(int c=threadIdx.x;c<EE;c+=256){
    float acc=0.f;
    const float* w = W1 + c*EE*3 + k3;
    for(int ci=0;ci<EE;ci++) acc += pr[ci]*w[ci*3];
    T1[(v*3+k3)*EE+c] = g1[c]*s*acc;
  }
}

__global__ void k_wr2(const float* __restrict__ W2, const float* __restrict__ g2,
                      unsigned short* __restrict__ Wr){
  int idx = blockIdx.x*256+threadIdx.x;
  if(idx >= EE*3*EE) return;
  int c = idx/1536; int r = idx%1536; int k3 = r/EE; int ci = r%EE;
  const float s = rsqrtf(1.f+1e-5f);
  Wr[idx] = f2b(g2[c]*s*W2[(c*EE+ci)*3+k3]);
}

__global__ void k_bb(const float* __restrict__ b1,const float* __restrict__ g1,const float* __restrict__ be1,
                     const float* __restrict__ b2,const float* __restrict__ g2,const float* __restrict__ be2,
                     float* __restrict__ bb1, float* __restrict__ bb2){
  int c = threadIdx.x + blockIdx.x*256; if(c>=EE) return;
  const float s = rsqrtf(1.f+1e-5f);
  bb1[c] = g1[c]*s*b1[c] + be1[c];
  bb2[c] = g2[c]*s*b2[c] + be2[c];
}

__global__ void k_b2(const float* __restrict__ bd, const float* __restrict__ Wih,
                     const float* __restrict__ bp, float* __restrict__ b2){
  int j = blockIdx.x*256+threadIdx.x; if(j>=4096) return;
  float acc = bd[j];
  const float* w = Wih + j*MELD;
  for(int m=0;m<MELD;m++) acc += w[m]*bp[m];
  b2[j] = acc;
}

__global__ void k_w2c(const float* __restrict__ Whh, const float* __restrict__ Wih,
                      const float* __restrict__ Wp, float* __restrict__ W2c){
  __shared__ float wl[8][MELD];
  int j0 = blockIdx.x*8; int k = blockIdx.y*256 + threadIdx.x;
  for(int i=threadIdx.x;i<8*MELD;i+=256) wl[i/MELD][i%MELD] = Wih[(j0+i/MELD)*MELD + (i%MELD)];
  __syncthreads();
  float acc[8];
  #pragma unroll
  for(int jj=0;jj<8;jj++) acc[jj]=Whh[(j0+jj)*HH+k];
  for(int m=0;m<MELD;m++){
    float wp = Wp[m*HH+k];
    #pragma unroll
    for(int jj=0;jj<8;jj++) acc[jj] += wl[jj][m]*wp;
  }
  #pragma unroll
  for(int jj=0;jj<8;jj++) W2c[(j0+jj)*HH+k] = acc[jj];
}

// ---- fragment packing ----
__global__ void k_pack(const float* __restrict__ src, unsigned short* __restrict__ dst,
                       int NKT, int K){
  int tile = blockIdx.x;
  int cg = tile>>3, wv = tile&7;
  int tot = NKT*64*8;
  for(int i=threadIdx.x; i<tot; i+=256){
    int kt = i>>9; int l = (i>>3)&63; int e = i&7;
    int j = (wv>>1)*1024 + cg*32 + (wv&1)*16 + (l&15);
    int k = ((l>>4)<<3) + kt*32 + e;
    dst[((size_t)(tile*NKT + kt)*64 + l)*8 + e] = f2b(src[(size_t)j*K + k]);
  }
}

__global__ void k_pack_pg(const float* __restrict__ Wp, const float* __restrict__ Wg,
                          unsigned short* __restrict__ dst){
  int nt = blockIdx.x; // 0..8
  for(int i=threadIdx.x; i<32*64*8; i+=256){
    int kt = i>>9; int l = (i>>3)&63; int e = i&7;
    int n = nt*16 + (l&15);
    int k = ((l>>4)<<3) + kt*32 + e;
    float v = (n<MELD)? Wp[(size_t)n*HH+k] : (n==MELD? Wg[k] : 0.f);
    dst[((size_t)(nt*32 + kt)*64 + l)*8 + e] = f2b(v);
  }
}

// ---- conv path ----

__global__ void k_pad(unsigned short* __restrict__ h1pb){
  int idx = blockIdx.x*256+threadIdx.x;
  int c = idx & 511; int b = idx >> 9;
  h1pb[((size_t)b*258)*EE + c] = 0;
  h1pb[((size_t)b*258 + 257)*EE + c] = 0;
}

__global__ void k_conv1(const int* __restrict__ x, const float* __restrict__ T1,
                        const float* __restrict__ bb1, unsigned short* __restrict__ h1pb){
  int idx = blockIdx.x*256+threadIdx.x;
  int c = idx & 511; int bt = idx >> 9; int t = bt & 255; int b = bt >> 8;
  float acc = bb1[c];
  if(t > 0)    acc += T1[(size_t)(x[b*TT+t-1]*3+0)*EE+c];
               acc += T1[(size_t)(x[b*TT+t  ]*3+1)*EE+c];
  if(t < TT-1) acc += T1[(size_t)(x[b*TT+t+1]*3+2)*EE+c];
  h1pb[((size_t)b*258 + t + 1)*EE + c] = f2b(fmaxf(acc, 0.f));
}

template<int NKT>
__device__ __forceinline__ void mm_seg_stream(const unsigned short* A, int lda,
    const unsigned short* Wrow, f32x4& acc0, f32x4& acc1, int l, int wv){
  int r0 = wv*32 + (l&15);
  int k8 = (l>>4)*8;
  const unsigned short* a0 = A + (size_t)r0*lda + k8;
  const unsigned short* a1 = a0 + 16*lda;
  const unsigned short* wp = Wrow + k8;
  #pragma unroll
  for(int kt=0;kt<NKT;kt++){
    bfv8 bv = *(const bfv8*)(const void*)(wp + kt*32);
    acc0 = mfma16(*(const bfv8*)(const void*)(a0 + kt*32), bv, acc0);
    acc1 = mfma16(*(const bfv8*)(const void*)(a1 + kt*32), bv, acc1);
  }
}

__global__ __launch_bounds__(256,2) void k_conv2mm(const unsigned short* __restrict__ h1pb,
    const unsigned short* __restrict__ Wr2b, const float* __restrict__ bb2,
    unsigned short* __restrict__ h2b){
  int b = blockIdx.x;    // 0..127
  int th = blockIdx.y;   // 0..1
  int nt = blockIdx.z;   // 0..31
  int tid=threadIdx.x; int wv=tid>>6, l=tid&63;
  const unsigned short* A = h1pb + ((size_t)b*258 + th*128)*EE;
  const unsigned short* Wrow = Wr2b + (size_t)(nt*16+(l&15))*1536;
  f32x4 acc0={0,0,0,0}, acc1={0,0,0,0};
  mm_seg_stream<48>(A, EE, Wrow, acc0, acc1, l, wv);
  int rr=(l>>4)*4, cc=l&15;
  int n = nt*16+cc;
  float bias = bb2[n];
  #pragma unroll
  for(int mi=0;mi<2;mi++){
    f32x4 acc = mi?acc1:acc0;
    int tb = th*128 + wv*32 + mi*16 + rr;
    #pragma unroll
    for(int q=0;q<4;q++){
      float v = fmaxf(acc[q]+bias, 0.f);
      h2b[((size_t)(tb+q)*BB + b)*EE + n] = f2b(v);
    }
  }
}

// ---- L2-resident atomic poll: atomics ALWAYS execute at the L2/TCC (never
// served stale from L1 -- the lesson of rounds 11/13 where plain/sc0 load
// polling spun forever). add-0 with sc0 returns the current value. ----
__device__ __forceinline__ unsigned l2_poll(unsigned* p){
  unsigned v;
  asm volatile("global_atomic_add %0, %1, %2, off sc0\n\ts_waitcnt vmcnt(0)"
               : "=v"(v) : "v"(p), "v"(0u) : "memory");
  return v;
}

// ---- barrier, two modes.
// FAST (32 WGs on one XCD, placement-verified):
//   arrive = syncthreads (vmcnt drain: h-stores in L2) + thread0 fetch_add on
//   a MONOTONIC workgroup-scope counter (no reset -> no reset/increment race);
//   the 32nd arriver derives the completed generation (old+1)>>5 and
//   broadcasts it via 32 workgroup-scope stores to 32 per-WG lines.
//   wait = thread0 polls ITS OWN line with an L2 atomic RMW (fresh by
//   construction, zero contention). Entirely intra-XCD: no coherence-point
//   round-trips.
// SLOW: round-8 agent-scope counting barrier (progress under any placement).
// Both count total completed barriers -> ge is a global monotonic target. ----
__device__ __forceinline__ void g_arrive(unsigned* cnt_slow, unsigned* gen_slow,
                                         unsigned* cnt_fast, unsigned* bcast_base,
                                         bool fastp){
  __syncthreads();
  if(threadIdx.x == 0){
    if(fastp){
      unsigned old = __hip_atomic_fetch_add(cnt_fast, 1u, __ATOMIC_RELAXED, __HIP_MEMORY_SCOPE_WORKGROUP);
      if((old & 31u) == 31u){
        unsigned g = (old + 1u) >> 5;
        #pragma unroll
        for(int i=0;i<32;i++)
          __hip_atomic_store(bcast_base + i*32, g, __ATOMIC_RELAXED, __HIP_MEMORY_SCOPE_WORKGROUP);
      }
    } else {
      unsigned old = __hip_atomic_fetch_add(cnt_slow, 1u, __ATOMIC_RELAXED, __HIP_MEMORY_SCOPE_AGENT);
      if(old == 31u){
        __hip_atomic_store(cnt_slow, 0u, __ATOMIC_RELAXED, __HIP_MEMORY_SCOPE_AGENT);
        __hip_atomic_fetch_add(gen_slow, 1u, __ATOMIC_RELAXED, __HIP_MEMORY_SCOPE_AGENT);
      }
    }
  }
}
__device__ __forceinline__ void g_wait(unsigned* gen_slow, unsigned* mybcast,
                                       unsigned ge, bool fastp){
  if(threadIdx.x == 0){
    if(fastp){
      while(l2_poll(mybcast) < ge) __builtin_amdgcn_s_sleep(1);
    } else {
      while(__hip_atomic_load(gen_slow, __ATOMIC_RELAXED, __HIP_MEMORY_SCOPE_AGENT) < ge)
        __builtin_amdgcn_s_sleep(1);
    }
  }
  asm volatile("" ::: "memory");
  __syncthreads();
}

// ---- h transport (round 12, proven): FAST = workgroup-scope store to XCD L2
// + sc0 reads (freshness via slot rotation > L1 capacity); SLOW = agent-scope
// at the coherence point. ----
__device__ __forceinline__ void h_store(unsigned int* ptr, unsigned int val, bool fastp){
  if(fastp) __hip_atomic_store(ptr, val, __ATOMIC_RELAXED, __HIP_MEMORY_SCOPE_WORKGROUP);
  else      __hip_atomic_store(ptr, val, __ATOMIC_RELAXED, __HIP_MEMORY_SCOPE_AGENT);
}
__device__ __forceinline__ void h_store64(unsigned long long* ptr, unsigned long long val, bool fastp){
  if(fastp) __hip_atomic_store(ptr, val, __ATOMIC_RELAXED, __HIP_MEMORY_SCOPE_WORKGROUP);
  else      __hip_atomic_store(ptr, val, __ATOMIC_RELAXED, __HIP_MEMORY_SCOPE_AGENT);
}

__device__ __forceinline__ void stage_h(unsigned short* hs, const unsigned short* slotp,
                                        int bg, int tid, bool fastp){
  if(fastp){
    const char* base = (const char*)(slotp + (size_t)(bg*16)*HH);
    #pragma unroll
    for(int jj=0;jj<2;jj++){
      int i0 = tid + (jj*2+0)*512, i1 = tid + (jj*2+1)*512;
      int r0 = i0>>7, c0 = i0&127, r1 = i1>>7, c1 = i1&127;
      int o0 = r0*2048 + c0*16,     o1 = r1*2048 + c1*16;
      u32x4 v0, v1;
      asm volatile(
        "global_load_dwordx4 %0, %2, off sc0\n\t"
        "global_load_dwordx4 %1, %3, off sc0\n\t"
        "s_waitcnt vmcnt(0)"
        : "=&v"(v0), "=&v"(v1)
        : "v"(base + o0), "v"(base + o1)
        : "memory");
      *(u32x4*)((char*)hs + (o0 ^ ((r0&7)<<4))) = v0;
      *(u32x4*)((char*)hs + (o1 ^ ((r1&7)<<4))) = v1;
    }
  } else {
    for(int i = tid; i < 4096; i += 512){
      int r = i >> 8, c8 = i & 255;
      const unsigned long long* p =
        (const unsigned long long*)(slotp + (size_t)(bg*16+r)*HH + c8*4);
      unsigned long long v = __hip_atomic_load(p, __ATOMIC_RELAXED, __HIP_MEMORY_SCOPE_AGENT);
      *(unsigned long long*)((char*)hs + ((r*2048 + c8*8) ^ ((r&7)<<4))) = v;
    }
  }
}

// ---- persistent recurrence: 256 WGs = 8 batch-groups x 32 col-groups.
// bg = bid&7: same-XCD group under round-robin dispatch (detected, not
// assumed; non-uniform groups fall back to the round-8 path). ----
__global__ __launch_bounds__(512,1) void k_recur(
  const unsigned short* __restrict__ h2b, unsigned short* __restrict__ ring,
  const unsigned short* __restrict__ WencR, const unsigned short* __restrict__ WihS,
  const unsigned short* __restrict__ W2cR, const unsigned short* __restrict__ WhhdS,
  const unsigned short* __restrict__ WpgS,
  const float* __restrict__ bhe, const float* __restrict__ bd, const float* __restrict__ b2,
  const float* __restrict__ bp, const float* __restrict__ bgp,
  unsigned int* __restrict__ bar,
  const int* __restrict__ tlen, const int* __restrict__ mlen,
  float* __restrict__ outmel, float* __restrict__ outgate)
{
  __shared__ __align__(16) unsigned short hs[16*1024];  // 32KB
  __shared__ __align__(16) unsigned short Xs[16*512];   // 16KB
  __shared__ float Gs[16][132];
  __shared__ unsigned s_ids[32];
  __shared__ int s_fast;

  const int bid = blockIdx.x;
  const int bg = bid & 7, cg = bid >> 3;
  const int tid = threadIdx.x;
  const int wvi = tid >> 6, l = tid & 63;
  const int tile = cg*8 + wvi;
  unsigned int* cnt_slow = bar + bg*32;
  unsigned int* gen_slow = bar + 256 + bg*32;
  unsigned int* xtab     = bar + 512;
  unsigned int* cnt_fast = bar + 1024 + bg*32;
  unsigned int* bcastb   = bar + 2048 + bg*1024;   // 32 lines, 128B apart
  unsigned int* mybcast  = bcastb + cg*32;
  unsigned int ge = 0;

  // ---- placement detection (cannot hang: all 256 co-resident WGs store
  // their id before any barrier) ----
  if(tid == 0){
    unsigned id;
    asm volatile("s_getreg_b32 %0, hwreg(HW_REG_XCC_ID)" : "=s"(id));
    __hip_atomic_store(xtab + bid, id + 1u, __ATOMIC_RELAXED, __HIP_MEMORY_SCOPE_AGENT);
  }
  if(tid < 32){
    unsigned v;
    do {
      v = __hip_atomic_load(xtab + (tid*8 + bg), __ATOMIC_RELAXED, __HIP_MEMORY_SCOPE_AGENT);
    } while(v == 0u);
    s_ids[tid] = v;
  }
  __syncthreads();
  if(tid == 0){
    int f = 1;
    for(int i=1;i<32;i++) if(s_ids[i] != s_ids[0]) f = 0;
    s_fast = f;
  }
  __syncthreads();
  const bool fastp = (s_fast != 0);

  const int fr = l & 15;
  const int hswz = (fr & 7) << 4;
  const int hbase = fr*2048 + ((l>>4)<<4);
  const int xbase = fr*1024 + ((l>>4)<<4);

  const int lr = tid >> 4;
  const int lc = (tid & 15) * 2;
  const int hcol = cg*32 + lc;
  float cs0 = 0.f, cs1 = 0.f;
  unsigned int hp = 0u;
  int mylen = 0;
  if(tid < 256) mylen = tlen[bg*16 + lr];

  // zero enc h_0 (slot 100)
  if(tid < 128){
    int r = tid >> 3, c4 = (tid & 7) * 4;
    unsigned long long* p = (unsigned long long*)
      (ring + (size_t)100*BB*HH + (size_t)(bg*16+r)*HH + cg*32 + c4);
    h_store64(p, 0ull, fastp);
  }
  ge++; g_arrive(cnt_slow, gen_slow, cnt_fast, bcastb, fastp);

  f32x4 bw[32];

  // ================= encoder: 256 steps =================
  {
    const f32x4* wsrc = (const f32x4*)(const void*)(WencR + ((size_t)(tile*32)*64 + l)*8);
    #pragma unroll
    for(int kt=0;kt<32;kt++) bw[kt] = wsrc[kt*64];
    #pragma unroll
    for(int kt=0;kt<32;kt++) asm volatile("" : "+v"(bw[kt]));
  }

  float ei0=0,ei1=0,ef0=0,ef1=0,eg0=0,eg1=0,eo0=0,eo1=0;
  if(tid < 256){
    ei0=bhe[hcol];      ei1=bhe[hcol+1];
    ef0=bhe[HH+hcol];   ef1=bhe[HH+hcol+1];
    eg0=bhe[2*HH+hcol]; eg1=bhe[2*HH+hcol+1];
    eo0=bhe[3*HH+hcol]; eo1=bhe[3*HH+hcol+1];
  }

  #pragma unroll 1
  for(int t=0;t<TT;t++){
    {
      const uint4* src = (const uint4*)(h2b + (size_t)(t*BB + bg*16)*EE);
      for(int i = tid; i < 1024; i += 512){
        int r = i >> 6, c16 = i & 63;
        uint4 v = src[r*64 + c16];
        *(uint4*)((char*)Xs + ((r*1024 + c16*16) ^ ((r&7)<<4))) = v;
      }
    }
    __syncthreads();
    f32x4 a0 = {0.f,0.f,0.f,0.f}, a1 = {0.f,0.f,0.f,0.f};
    {
      const unsigned short* wsrc = WihS + (size_t)tile*16*64*8;
      #pragma unroll
      for(int kt=0;kt<16;kt+=2){
        bfv8 wf0 = *(const bfv8*)(const void*)(wsrc + ((size_t)kt*64 + l)*8);
        bfv8 wf1 = *(const bfv8*)(const void*)(wsrc + ((size_t)(kt+1)*64 + l)*8);
        bfv8 xv0 = *(const bfv8*)(const void*)((const char*)Xs + ((xbase + kt*64) ^ hswz));
        bfv8 xv1 = *(const bfv8*)(const void*)((const char*)Xs + ((xbase + (kt+1)*64) ^ hswz));
        a0 = mfma16(xv0, wf0, a0);
        a1 = mfma16(xv1, wf1, a1);
      }
    }
    g_wait(gen_slow, mybcast, ge, fastp);   // h_t ready
    stage_h(hs, ring + (size_t)(100 + (t&1))*BB*HH, bg, tid, fastp);
    __syncthreads();
    #pragma unroll
    for(int kt=0;kt<32;kt+=2){
      bfv8 hv0 = *(const bfv8*)(const void*)((const char*)hs + ((hbase + kt*64) ^ hswz));
      bfv8 hv1 = *(const bfv8*)(const void*)((const char*)hs + ((hbase + (kt+1)*64) ^ hswz));
      a0 = mfma16(hv0, __builtin_bit_cast(bfv8, bw[kt]), a0);
      a1 = mfma16(hv1, __builtin_bit_cast(bfv8, bw[kt+1]), a1);
    }
    {
      f32x4 acc = a0 + a1;
      int rr = (l>>4)*4;
      #pragma unroll
      for(int q=0;q<4;q++) Gs[rr+q][wvi*16 + fr] = acc[q];
    }
    __syncthreads();
    if(tid < 256){
      float gi0 = Gs[lr][lc]    + ei0, gi1 = Gs[lr][lc+1] + ei1;
      float gf0 = Gs[lr][32+lc] + ef0, gf1 = Gs[lr][33+lc] + ef1;
      float gg0 = Gs[lr][64+lc] + eg0, gg1 = Gs[lr][65+lc] + eg1;
      float go0 = Gs[lr][96+lc] + eo0, go1 = Gs[lr][97+lc] + eo1;
      float c20 = sigm(gf0)*cs0 + sigm(gi0)*tanhf(gg0);
      float c21 = sigm(gf1)*cs1 + sigm(gi1)*tanhf(gg1);
      float h20 = sigm(go0)*tanhf(c20);
      float h21 = sigm(go1)*tanhf(c21);
      if(t < mylen){
        cs0 = c20; cs1 = c21;
        hp = (unsigned)f2b(h20) | ((unsigned)f2b(h21)<<16);
      }
      unsigned short* outslot = (t==TT-1) ? (ring + (size_t)99*BB*HH)
                                          : (ring + (size_t)(100 + ((t+1)&1))*BB*HH);
      h_store((unsigned int*)(outslot + (size_t)(bg*16+lr)*HH + hcol), hp, fastp);
    }
    ge++; g_arrive(cnt_slow, gen_slow, cnt_fast, bcastb, fastp);
  }

  // ================= decoder: 800 steps =================
  {
    const f32x4* wsrc = (const f32x4*)(const void*)(W2cR + ((size_t)(tile*32)*64 + l)*8);
    #pragma unroll
    for(int kt=0;kt<32;kt++) bw[kt] = wsrc[kt*64];
    #pragma unroll
    for(int kt=0;kt<32;kt++) asm volatile("" : "+v"(bw[kt]));
  }

  float di0=0,di1=0,df0=0,df1=0,dg0=0,dg1=0,do0=0,do1=0;
  if(tid < 256){
    di0=b2[hcol];      di1=b2[hcol+1];
    df0=b2[HH+hcol];   df1=b2[HH+hcol+1];
    dg0=b2[2*HH+hcol]; dg1=b2[2*HH+hcol+1];
    do0=b2[3*HH+hcol]; do1=b2[3*HH+hcol+1];
  }

  #pragma unroll 1
  for(int t=0;t<TMEL;t++){
    g_wait(gen_slow, mybcast, ge, fastp);   // s_t ready
    const unsigned short* slotin = (t==0) ? ring + (size_t)99*BB*HH
                                          : ring + (size_t)((t-1)%100)*BB*HH;
    stage_h(hs, slotin, bg, tid, fastp);
    __syncthreads();
    f32x4 a0 = {0.f,0.f,0.f,0.f}, a1 = {0.f,0.f,0.f,0.f};
    if(t == 0){
      const unsigned short* wsrc = WhhdS + (size_t)tile*32*64*8;
      #pragma unroll
      for(int kt=0;kt<32;kt+=2){
        bfv8 wf0 = *(const bfv8*)(const void*)(wsrc + ((size_t)kt*64 + l)*8);
        bfv8 wf1 = *(const bfv8*)(const void*)(wsrc + ((size_t)(kt+1)*64 + l)*8);
        bfv8 hv0 = *(const bfv8*)(const void*)((const char*)hs + ((hbase + kt*64) ^ hswz));
        bfv8 hv1 = *(const bfv8*)(const void*)((const char*)hs + ((hbase + (kt+1)*64) ^ hswz));
        a0 = mfma16(hv0, wf0, a0);
        a1 = mfma16(hv1, wf1, a1);
      }
    } else {
      #pragma unroll
      for(int kt=0;kt<32;kt+=2){
        bfv8 hv0 = *(const bfv8*)(const void*)((const char*)hs + ((hbase + kt*64) ^ hswz));
        bfv8 hv1 = *(const bfv8*)(const void*)((const char*)hs + ((hbase + (kt+1)*64) ^ hswz));
        a0 = mfma16(hv0, __builtin_bit_cast(bfv8, bw[kt]), a0);
        a1 = mfma16(hv1, __builtin_bit_cast(bfv8, bw[kt+1]), a1);
      }
    }
    {
      f32x4 acc = a0 + a1;
      int rr = (l>>4)*4;
      #pragma unroll
      for(int q=0;q<4;q++) Gs[rr+q][wvi*16 + fr] = acc[q];
    }
    __syncthreads();
    if(tid < 256){
      float bi0=di0,bi1=di1,bf0=df0,bf1=df1,bg0=dg0,bg1=dg1,bo0=do0,bo1=do1;
      if(t==0){
        bi0=bd[hcol];      bi1=bd[hcol+1];
        bf0=bd[HH+hcol];   bf1=bd[HH+hcol+1];
        bg0=bd[2*HH+hcol]; bg1=bd[2*HH+hcol+1];
        bo0=bd[3*HH+hcol]; bo1=bd[3*HH+hcol+1];
      }
      float gi0 = Gs[lr][lc]    + bi0, gi1 = Gs[lr][lc+1] + bi1;
      float gf0 = Gs[lr][32+lc] + bf0, gf1 = Gs[lr][33+lc] + bf1;
      float gg0 = Gs[lr][64+lc] + bg0, gg1 = Gs[lr][65+lc] + bg1;
      float go0 = Gs[lr][96+lc] + bo0, go1 = Gs[lr][97+lc] + bo1;
      float c20 = sigm(gf0)*cs0 + sigm(gi0)*tanhf(gg0);
      float c21 = sigm(gf1)*cs1 + sigm(gi1)*tanhf(gg1);
      cs0 = c20; cs1 = c21;
      float h20 = sigm(go0)*tanhf(c20);
      float h21 = sigm(go1)*tanhf(c21);
      unsigned int hn = (unsigned)f2b(h20) | ((unsigned)f2b(h21)<<16);
      unsigned short* outslot = ring + (size_t)(t%100)*BB*HH;
      h_store((unsigned int*)(outslot + (size_t)(bg*16+lr)*HH + hcol), hn, fastp);
    }
    ge++; g_arrive(cnt_slow, gen_slow, cnt_fast, bcastb, fastp);

    if((t%100)==99){
      g_wait(gen_slow, mybcast, ge, fastp);   // all 100 slots final
      int tbase = t - 99;
      #pragma unroll 1
      for(int s = cg; s < 100; s += 32){
        stage_h(hs, ring + (size_t)s*BB*HH, bg, tid, fastp);
        __syncthreads();
        int tout = tbase + s;
        #pragma unroll 1
        for(int pass=0; pass<2; pass++){
          int nt = (pass==0) ? wvi : 8;
          if(pass==1 && wvi!=0) break;
          const unsigned short* wsrc = WpgS + (size_t)nt*32*64*8;
          f32x4 acc = {0.f,0.f,0.f,0.f};
          #pragma unroll
          for(int kt=0;kt<32;kt++){
            bfv8 wf = *(const bfv8*)(const void*)(wsrc + ((size_t)kt*64 + l)*8);
            bfv8 hv = *(const bfv8*)(const void*)((const char*)hs + ((hbase + kt*64) ^ hswz));
            acc = mfma16(hv, wf, acc);
          }
          int n = nt*16 + fr;
          #pragma unroll
          for(int q=0;q<4;q++){
            int b = bg*16 + (l>>4)*4 + q;
            bool msk = tout > mlen[b];
            if(n < MELD)
              outmel[((size_t)b*TMEL + tout)*MELD + n] = msk ? 0.f : acc[q]+bp[n];
            else if(n == MELD)
              outgate[(size_t)b*TMEL + tout] = msk ? 1000.f : acc[q]+bgp[0];
          }
        }
        __syncthreads();
      }
      ge++; g_arrive(cnt_slow, gen_slow, cnt_fast, bcastb, fastp);
    }
  }
}

__global__ void k_mask(const int* __restrict__ mlen, float* __restrict__ om){
  int idx=blockIdx.x*256+threadIdx.x; if(idx>=BB*TMEL) return;
  int b=idx/TMEL, t=idx%TMEL;
  om[idx] = (t > mlen[b]) ? 1.f : 0.f;
}

extern "C" void kernel_launch(void* const* d_in, const int* in_sizes, int n_in,
                              void* d_out, int out_size, void* d_ws, size_t ws_size,
                              hipStream_t stream){
  (void)in_sizes; (void)n_in; (void)out_size; (void)ws_size;
  const int*   x    = (const int*)d_in[0];
  const int*   tlen = (const int*)d_in[1];
  const int*   mlen = (const int*)d_in[3];
  const float* emb  = (const float*)d_in[4];
  const float* elW  = (const float*)d_in[5];
  const float* elb  = (const float*)d_in[6];
  const float* c1W  = (const float*)d_in[7];
  const float* c1b  = (const float*)d_in[8];
  const float* g1   = (const float*)d_in[9];
  const float* be1  = (const float*)d_in[10];
  const float* c2W  = (const float*)d_in[11];
  const float* c2b  = (const float*)d_in[12];
  const float* g2   = (const float*)d_in[13];
  const float* be2  = (const float*)d_in[14];
  const float* Wihe = (const float*)d_in[15];
  const float* Whhe = (const float*)d_in[16];
  const float* bhe  = (const float*)d_in[17];
  const float* Wihd = (const float*)d_in[18];
  const float* Whhd = (const float*)d_in[19];
  const float* bhd  = (const float*)d_in[20];
  const float* Wp   = (const float*)d_in[21];
  const float* bp   = (const float*)d_in[22];
  const float* Wg   = (const float*)d_in[23];
  const float* bg   = (const float*)d_in[24];

  float* ws = (float*)d_ws;
  float* proj = ws + OFF_PROJ;
  float* T1   = ws + OFF_T1;
  unsigned short* Wr2b = (unsigned short*)(ws + OFF_WR2);
  float* bb1 = ws + OFF_BB1;
  float* bb2 = ws + OFF_BB2;
  float* b2  = ws + OFF_B2;
  float* W2c = ws + OFF_W2C;
  unsigned int* bar = (unsigned int*)(ws + OFF_BAR);
  unsigned short* WencR = (unsigned short*)(ws + OFF_WENCR);
  unsigned short* WihS  = (unsigned short*)(ws + OFF_WIHS);
  unsigned short* W2cR  = (unsigned short*)(ws + OFF_W2CR);
  unsigned short* WhhdS = (unsigned short*)(ws + OFF_WHHDS);
  unsigned short* WpgS  = (unsigned short*)(ws + OFF_WPGS);
  unsigned short* h2b   = (unsigned short*)(ws + OFF_H2B);
  unsigned short* h1pb  = (unsigned short*)(ws + OFF_RING); // conv scratch
  unsigned short* ring  = (unsigned short*)(ws + OFF_RING); // alias after conv2

  float* outmel  = (float*)d_out;
  float* outgate = outmel + (size_t)BB*TMEL*MELD;
  float* outmask = outgate + (size_t)BB*TMEL;

  hipMemsetAsync(bar, 0, 40960, stream);   // cnt/gen + xtab + fast cnt + bcast

  k_proj<<<VV,256,0,stream>>>(emb, elW, elb, proj);
  k_t1<<<dim3(VV,3),256,0,stream>>>(proj, c1W, g1, T1);
  k_wr2<<<(EE*3*EE+255)/256,256,0,stream>>>(c2W, g2, Wr2b);
  k_bb<<<2,256,0,stream>>>(c1b,g1,be1,c2b,g2,be2,bb1,bb2);
  k_b2<<<16,256,0,stream>>>(bhd, Wihd, bp, b2);
  k_w2c<<<dim3(4096/8,HH/256),256,0,stream>>>(Whhd, Wihd, Wp, W2c);
  k_pack<<<256,256,0,stream>>>(Whhe, WencR, 32, 1024);
  k_pack<<<256,256,0,stream>>>(Wihe, WihS, 16, 512);
  k_pack<<<256,256,0,stream>>>(W2c,  W2cR, 32, 1024);
  k_pack<<<256,256,0,stream>>>(Whhd, WhhdS, 32, 1024);
  k_pack_pg<<<9,256,0,stream>>>(Wp, Wg, WpgS);
  k_pad<<<256,256,0,stream>>>(h1pb);
  k_conv1<<<65536,256,0,stream>>>(x, T1, bb1, h1pb);
  k_conv2mm<<<dim3(BB,2,32),256,0,stream>>>(h1pb, Wr2b, bb2, h2b);

  void* kargs[] = {
    (void*)&h2b, (void*)&ring, (void*)&WencR, (void*)&WihS, (void*)&W2cR, (void*)&WhhdS,
    (void*)&WpgS, (void*)&bhe, (void*)&bhd, (void*)&b2, (void*)&bp, (void*)&bg,
    (void*)&bar, (void*)&tlen, (void*)&mlen, (void*)&outmel, (void*)&outgate
  };
  hipLaunchCooperativeKernel((void*)k_recur, dim3(256), dim3(512), kargs, 0u, stream);

  k_mask<<<(BB*TMEL+255)/256,256,0,stream>>>(mlen, outmask);
}